// Round 1
// baseline (1266.761 us; speedup 1.0000x reference)
//
#include <hip/hip_runtime.h>

// Problem: B=8, T=1024, D=128, TEMP=0.1, WEIGHT=1.0
// 56 ordered pairs (i,j), i!=j.
// Phase 1: scores1[t,s] = -|e1_t - e2_s|^2 / 12.8  (softmax over s) -> nn_t = sum_s beta*e2_s
//   (row-constant |e1_t|^2 dropped: softmax-invariant; clamp max(d2,0) numerically dead)
// Phase 2: scores2[t,s] = -|nn_t - e1_s|^2 / 12.8  (softmax over s) -> time_pred_t = sum_s beta*sp_s
// loss = mean over (56*1024) of (time_pred - sp_t)^2

#define T_ 1024
#define D_ 128
#define NPAIR 56
#define INV_SCALE 0.078125f   // 1/(128*0.1)
#define KT_STRIDE 132         // 64x128 key tile padded to 132 floats/row (16B-aligned rows)

__device__ __forceinline__ float waveMax(float v) {
#pragma unroll
  for (int k = 32; k >= 1; k >>= 1) v = fmaxf(v, __shfl_xor(v, k, 64));
  return v;
}
__device__ __forceinline__ float waveSum(float v) {
#pragma unroll
  for (int k = 32; k >= 1; k >>= 1) v += __shfl_xor(v, k, 64);
  return v;
}

// one wave per row: row norms + steps
__global__ __launch_bounds__(64) void precompute_kernel(
    const float* __restrict__ embs, const int* __restrict__ frame_idxs,
    const int* __restrict__ video_len, float* __restrict__ norms,
    float* __restrict__ steps) {
  int row = blockIdx.x;          // 0..8191
  int lane = threadIdx.x;        // 0..63
  const float* e = embs + (size_t)row * D_;
  float v0 = e[lane], v1 = e[lane + 64];
  float s = waveSum(v0 * v0 + v1 * v1);
  if (lane == 0) {
    norms[row] = s;
    int b = row >> 10;
    steps[row] = (float)frame_idxs[row] / (float)video_len[b];
  }
}

__global__ __launch_bounds__(256) void tcc_main(
    const float* __restrict__ embs, const float* __restrict__ norms,
    const float* __restrict__ steps, float* __restrict__ loss_acc) {
  __shared__ float kt[64 * KT_STRIDE];   // 33792 B key tile
  __shared__ float qv[16 * D_];          // 8192 B  query rows (phase1: e1 rows; phase2: nn rows)
  __shared__ float p_lds[4][4][64];      // 4096 B  per-wave softmax weights
  __shared__ float blk_loss[4];

  const int pair = blockIdx.y;
  const int i = pair / 7;
  const int r = pair % 7;
  const int j = r + (r >= i ? 1 : 0);
  const int t0 = blockIdx.x * 16;
  const int tid = threadIdx.x;
  const int lane = tid & 63;
  const int w = tid >> 6;

  const float* e1 = embs + (size_t)i * T_ * D_;
  const float* e2 = embs + (size_t)j * T_ * D_;

  // load 16 query rows of e1 into qv
#pragma unroll
  for (int k = 0; k < 2; k++) {
    int idx = tid + k * 256;             // float4 index, 512 total
    int row = idx >> 5, c = idx & 31;
    ((float4*)qv)[idx] = ((const float4*)(e1 + (size_t)(t0 + row) * D_))[c];
  }

  float m1[4], L1[4], a0[4], a1[4];
#pragma unroll
  for (int q = 0; q < 4; q++) { m1[q] = -1e30f; L1[q] = 0.f; a0[q] = 0.f; a1[q] = 0.f; }

  // ---------------- phase 1: e1 queries vs e2 keys, accumulate nn ----------------
  for (int st = 0; st < 16; st++) {
    const int sbase = st * 64;
    __syncthreads();
#pragma unroll
    for (int k = 0; k < 8; k++) {
      int idx = k * 256 + tid;
      int row = idx >> 5, c = idx & 31;
      float4 g = ((const float4*)(e2 + (size_t)(sbase + row) * D_))[c];
      *(float4*)&kt[row * KT_STRIDE + c * 4] = g;
    }
    __syncthreads();

    float n2s = norms[j * T_ + sbase + lane];
    float dot[4] = {0.f, 0.f, 0.f, 0.f};
#pragma unroll
    for (int c = 0; c < 32; c++) {
      float4 kf = *(const float4*)&kt[lane * KT_STRIDE + c * 4];
#pragma unroll
      for (int q = 0; q < 4; q++) {
        float4 qf = *(const float4*)&qv[(w * 4 + q) * D_ + c * 4];
        dot[q] += kf.x * qf.x + kf.y * qf.y + kf.z * qf.z + kf.w * qf.w;
      }
    }
#pragma unroll
    for (int q = 0; q < 4; q++) {
      float sc = (2.f * dot[q] - n2s) * INV_SCALE;
      float tmax = waveMax(sc);
      float nm = fmaxf(m1[q], tmax);
      float scale = __expf(m1[q] - nm);
      float p = __expf(sc - nm);
      float ps = waveSum(p);
      L1[q] = L1[q] * scale + ps;
      a0[q] *= scale;
      a1[q] *= scale;
      m1[q] = nm;
      p_lds[w][q][lane] = p;
    }
    // PV: acc_d += sum_s p_s * e2[s,d]; lane owns d=lane and d=lane+64
#pragma unroll 4
    for (int s4 = 0; s4 < 64; s4 += 4) {
      float4 pw0 = *(const float4*)&p_lds[w][0][s4];
      float4 pw1 = *(const float4*)&p_lds[w][1][s4];
      float4 pw2 = *(const float4*)&p_lds[w][2][s4];
      float4 pw3 = *(const float4*)&p_lds[w][3][s4];
      float pa0[4] = {pw0.x, pw0.y, pw0.z, pw0.w};
      float pa1[4] = {pw1.x, pw1.y, pw1.z, pw1.w};
      float pa2[4] = {pw2.x, pw2.y, pw2.z, pw2.w};
      float pa3[4] = {pw3.x, pw3.y, pw3.z, pw3.w};
#pragma unroll
      for (int u = 0; u < 4; u++) {
        float k0 = kt[(s4 + u) * KT_STRIDE + lane];
        float k1 = kt[(s4 + u) * KT_STRIDE + 64 + lane];
        a0[0] += pa0[u] * k0; a1[0] += pa0[u] * k1;
        a0[1] += pa1[u] * k0; a1[1] += pa1[u] * k1;
        a0[2] += pa2[u] * k0; a1[2] += pa2[u] * k1;
        a0[3] += pa3[u] * k0; a1[3] += pa3[u] * k1;
      }
    }
  }

  // write normalized nn into qv (each wave touches only its own 4 rows)
#pragma unroll
  for (int q = 0; q < 4; q++) {
    float invL = 1.0f / L1[q];
    qv[(w * 4 + q) * D_ + lane] = a0[q] * invL;
    qv[(w * 4 + q) * D_ + 64 + lane] = a1[q] * invL;
  }

  // ---------------- phase 2: nn queries vs e1 keys, V = sp scalar ----------------
  float m2[4], L2[4], tp[4];
#pragma unroll
  for (int q = 0; q < 4; q++) { m2[q] = -1e30f; L2[q] = 0.f; tp[q] = 0.f; }

  for (int st = 0; st < 16; st++) {
    const int sbase = st * 64;
    __syncthreads();
#pragma unroll
    for (int k = 0; k < 8; k++) {
      int idx = k * 256 + tid;
      int row = idx >> 5, c = idx & 31;
      float4 g = ((const float4*)(e1 + (size_t)(sbase + row) * D_))[c];
      *(float4*)&kt[row * KT_STRIDE + c * 4] = g;
    }
    __syncthreads();

    float n1s = norms[i * T_ + sbase + lane];
    float sps = steps[i * T_ + sbase + lane];
    float dot[4] = {0.f, 0.f, 0.f, 0.f};
#pragma unroll
    for (int c = 0; c < 32; c++) {
      float4 kf = *(const float4*)&kt[lane * KT_STRIDE + c * 4];
#pragma unroll
      for (int q = 0; q < 4; q++) {
        float4 qf = *(const float4*)&qv[(w * 4 + q) * D_ + c * 4];
        dot[q] += kf.x * qf.x + kf.y * qf.y + kf.z * qf.z + kf.w * qf.w;
      }
    }
#pragma unroll
    for (int q = 0; q < 4; q++) {
      float sc = (2.f * dot[q] - n1s) * INV_SCALE;
      float nm = fmaxf(m2[q], sc);
      float scale = __expf(m2[q] - nm);
      float p = __expf(sc - nm);
      L2[q] = L2[q] * scale + p;
      tp[q] = tp[q] * scale + p * sps;
      m2[q] = nm;
    }
  }

  // epilogue: combine per-lane online softmax states, MSE accumulate
  float local = 0.f;
#pragma unroll
  for (int q = 0; q < 4; q++) {
    float M = waveMax(m2[q]);
    float z = __expf(m2[q] - M);
    float Ls = waveSum(L2[q] * z);
    float Ts = waveSum(tp[q] * z);
    float time_pred = Ts / Ls;
    float tt = steps[i * T_ + t0 + w * 4 + q];
    float d = time_pred - tt;
    local += d * d;
  }
  if (lane == 0) blk_loss[w] = local;
  __syncthreads();
  if (tid == 0) {
    float s = blk_loss[0] + blk_loss[1] + blk_loss[2] + blk_loss[3];
    atomicAdd(loss_acc, s);
  }
}

__global__ void finalize_kernel(const float* __restrict__ acc, float* __restrict__ out) {
  out[0] = acc[0] * (1.0f / (float)(NPAIR * T_));  // WEIGHT = 1.0
}

extern "C" void kernel_launch(void* const* d_in, const int* in_sizes, int n_in,
                              void* d_out, int out_size, void* d_ws, size_t ws_size,
                              hipStream_t stream) {
  const float* embs = (const float*)d_in[0];
  const int* frame_idxs = (const int*)d_in[1];
  const int* video_len = (const int*)d_in[2];
  float* out = (float*)d_out;

  float* acc = (float*)d_ws;                          // 1 float @ offset 0
  float* norms = (float*)((char*)d_ws + 256);         // 8192 floats
  float* steps = norms + 8 * T_;                      // 8192 floats

  hipMemsetAsync(d_ws, 0, 256, stream);
  precompute_kernel<<<dim3(8 * T_), dim3(64), 0, stream>>>(embs, frame_idxs, video_len, norms, steps);
  tcc_main<<<dim3(T_ / 16, NPAIR), dim3(256), 0, stream>>>(embs, norms, steps, acc);
  finalize_kernel<<<1, 1, 0, stream>>>(acc, out);
}

// Round 2
// 229.342 us; speedup vs baseline: 5.5235x; 5.5235x over previous
//
#include <hip/hip_runtime.h>

// B=8, T=1024, D=128, TEMP=0.1, WEIGHT=1.0. 56 ordered pairs (i,j), i!=j.
// z1[t,s] = (2*e1_t.e2_s - |e2_s|^2)/12.8 (+row const dropped; softmax-invariant)
// p = exp(z1) (NO max subtraction: z1 in [-26,+15] provably, fp32 exp safe)
// nn_t = (sum_s p*e2_s)/L ; z2[t,s] = (2*nn_t.e1_s - |e1_s|^2)/12.8
// time_pred = sum_s exp(z2)*sp_s / sum_s exp(z2); loss = mean (pred - sp_t)^2
// log2(e) folded into QSCALE/NSCALE so exp = single v_exp_f32.

#define T_ 1024
#define D_ 128
#define NPAIR 56
#define QSCALE 0.22542110013890052f   // (2/12.8)*log2(e)
#define NSCALE 0.11271055006945026f   // (1/12.8)*log2(e)
#define KTS 136   // kt row stride (64 rows x 128 bf16, +8 pad -> 2-way-free b128 reads)
#define VTS 72    // vt row stride (128 rows x 64 bf16, +8 pad)
#define NNS 136   // per-wave nn/p buffer row stride

typedef short short8 __attribute__((ext_vector_type(8)));
typedef unsigned short u16x8 __attribute__((ext_vector_type(8)));
typedef float f32x4 __attribute__((ext_vector_type(4)));

__device__ __forceinline__ unsigned short f2bf(float f) {
  unsigned u = __float_as_uint(f);
  u += 0x7fff + ((u >> 16) & 1);            // RNE
  return (unsigned short)(u >> 16);
}

__device__ __forceinline__ short8 pack8(float4 a, float4 b, float s) {
  short8 r;
  r[0] = (short)f2bf(a.x * s); r[1] = (short)f2bf(a.y * s);
  r[2] = (short)f2bf(a.z * s); r[3] = (short)f2bf(a.w * s);
  r[4] = (short)f2bf(b.x * s); r[5] = (short)f2bf(b.y * s);
  r[6] = (short)f2bf(b.z * s); r[7] = (short)f2bf(b.w * s);
  return r;
}

__device__ __forceinline__ float waveSum(float v) {
#pragma unroll
  for (int k = 32; k >= 1; k >>= 1) v += __shfl_xor(v, k, 64);
  return v;
}
__device__ __forceinline__ float quadSum(float v) {
  v += __shfl_xor(v, 1, 64); v += __shfl_xor(v, 2, 64);
  v += __shfl_xor(v, 4, 64); v += __shfl_xor(v, 8, 64);
  return v;
}

// ---- norms (pre-scaled by NSCALE) + steps; one wave per row ----
__global__ __launch_bounds__(256) void norm_kernel(
    const float* __restrict__ embs, const int* __restrict__ fi,
    const int* __restrict__ vl, float* __restrict__ ns, float* __restrict__ steps) {
  int row = blockIdx.x * 4 + (threadIdx.x >> 6);
  int lane = threadIdx.x & 63;
  const float* e = embs + (size_t)row * D_;
  float v0 = e[lane], v1 = e[lane + 64];
  float s = waveSum(v0 * v0 + v1 * v1);
  if (lane == 0) {
    ns[row] = s * NSCALE;
    steps[row] = (float)fi[row] / (float)vl[row >> 10];
  }
}

// ---- fp32 -> bf16 row-major + per-batch transposed copy ----
__global__ __launch_bounds__(256) void convert_kernel(
    const float* __restrict__ embs, unsigned short* __restrict__ ebf,
    unsigned short* __restrict__ ebfT) {
  __shared__ unsigned short tile[64 * 132];
  int b = blockIdx.y;
  int t0 = blockIdx.x * 64;
  int tid = threadIdx.x;
#pragma unroll
  for (int c = 0; c < 8; c++) {
    int idx = c * 256 + tid;              // 2048 float4 chunks
    int row = idx >> 5, col4 = idx & 31;
    float4 g = ((const float4*)(embs + (size_t)(b * T_ + t0 + row) * D_))[col4];
    ushort4 v;
    v.x = f2bf(g.x); v.y = f2bf(g.y); v.z = f2bf(g.z); v.w = f2bf(g.w);
    *(ushort4*)(ebf + (size_t)(b * T_ + t0 + row) * D_ + col4 * 4) = v;
    *(ushort4*)&tile[row * 132 + col4 * 4] = v;
  }
  __syncthreads();
#pragma unroll
  for (int c = 0; c < 8; c++) {
    int idx = c * 256 + tid;              // 128 d x 16 chunks of 4 t
    int d = idx >> 4, tb = (idx & 15) * 4;
    ushort4 v;
    v.x = tile[(tb + 0) * 132 + d];
    v.y = tile[(tb + 1) * 132 + d];
    v.z = tile[(tb + 2) * 132 + d];
    v.w = tile[(tb + 3) * 132 + d];
    *(ushort4*)(ebfT + (size_t)(b * D_ + d) * T_ + t0 + tb) = v;
  }
}

__global__ __launch_bounds__(256) void tcc_main(
    const float* __restrict__ embs, const unsigned short* __restrict__ ebf,
    const unsigned short* __restrict__ ebfT, const float* __restrict__ ns,
    const float* __restrict__ steps, float* __restrict__ loss_acc) {
  __shared__ unsigned short kt[64 * KTS];     // 17408 B  key tile [s][d]
  __shared__ unsigned short vt[128 * VTS];    // 18432 B  V tile   [d][s]
  __shared__ unsigned short un[4 * 16 * NNS]; // 17408 B  per-wave p (phase1) / nn (phase2)
  __shared__ float bl[4];

  const int pair = blockIdx.y;
  const int i = pair / 7;
  const int r = pair % 7;
  const int j = r + (r >= i ? 1 : 0);
  const int t0 = blockIdx.x * 64;
  const int tid = threadIdx.x;
  const int lane = tid & 63;
  const int w = tid >> 6;
  const int quad = lane >> 4;
  const int l15 = lane & 15;

  // A-frags: Q = e1 rows (t = t0 + w*16 + l15), scaled by QSCALE
  short8 qf[4];
  {
    const float* qp = embs + (size_t)(i * T_ + t0 + w * 16 + l15) * D_ + quad * 8;
#pragma unroll
    for (int k = 0; k < 4; k++) {
      float4 g0 = *(const float4*)(qp + k * 32);
      float4 g1 = *(const float4*)(qp + k * 32 + 4);
      qf[k] = pack8(g0, g1, QSCALE);
    }
  }

  const unsigned short* ktb = kt + l15 * KTS + quad * 8;
  const unsigned short* vtb = vt + l15 * VTS + quad * 8;
  unsigned short* ptw = un + w * (16 * NNS);   // phase-1 p buffer, row stride VTS

  f32x4 o[8];
#pragma unroll
  for (int n = 0; n < 8; n++) o[n] = (f32x4){0.f, 0.f, 0.f, 0.f};
  float Lp[4] = {0.f, 0.f, 0.f, 0.f};

  // ---------------- phase 1: Q=e1, K=V=e2 ----------------
  for (int st = 0; st < 16; st++) {
    const int sbase = st * 64;
    __syncthreads();
    {
      const unsigned short* src = ebf + (size_t)(j * T_ + sbase) * D_;
#pragma unroll
      for (int c = 0; c < 4; c++) {
        int idx = c * 256 + tid;
        int row = idx >> 4, cp = (idx & 15) * 8;
        *(u16x8*)&kt[row * KTS + cp] = *(const u16x8*)(src + row * D_ + cp);
      }
      const unsigned short* srcT = ebfT + (size_t)(j * D_) * T_ + sbase;
#pragma unroll
      for (int c = 0; c < 4; c++) {
        int idx = c * 256 + tid;
        int d = idx >> 3, cp = (idx & 7) * 8;
        *(u16x8*)&vt[d * VTS + cp] = *(const u16x8*)(srcT + (size_t)d * T_ + cp);
      }
    }
    __syncthreads();

    const float* nsp = ns + j * T_ + sbase + l15;
#pragma unroll
    for (int n = 0; n < 4; n++) {
      f32x4 acc = (f32x4){0.f, 0.f, 0.f, 0.f};
#pragma unroll
      for (int k = 0; k < 4; k++) {
        short8 bf = *(const short8*)(ktb + n * 16 * KTS + k * 32);
        acc = __builtin_amdgcn_mfma_f32_16x16x32_bf16(qf[k], bf, acc, 0, 0, 0);
      }
      float nv = nsp[n * 16];
#pragma unroll
      for (int rg = 0; rg < 4; rg++) {
        float pv = __builtin_amdgcn_exp2f(acc[rg] - nv);
        Lp[rg] += pv;
        ptw[(quad * 4 + rg) * VTS + n * 16 + l15] = f2bf(pv);
      }
    }
    // PV: O[t][d] += P[t][s] * V[s][d]
    short8 pa0 = *(const short8*)(ptw + l15 * VTS + quad * 8);
    short8 pa1 = *(const short8*)(ptw + l15 * VTS + 32 + quad * 8);
#pragma unroll
    for (int n2 = 0; n2 < 8; n2++) {
      short8 b0 = *(const short8*)(vtb + n2 * 16 * VTS);
      short8 b1 = *(const short8*)(vtb + n2 * 16 * VTS + 32);
      o[n2] = __builtin_amdgcn_mfma_f32_16x16x32_bf16(pa0, b0, o[n2], 0, 0, 0);
      o[n2] = __builtin_amdgcn_mfma_f32_16x16x32_bf16(pa1, b1, o[n2], 0, 0, 0);
    }
  }

  // normalize nn, write per-wave LDS, reload as A-frags (QSCALE folded into 1/L)
#pragma unroll
  for (int rg = 0; rg < 4; rg++) Lp[rg] = QSCALE / quadSum(Lp[rg]);
  unsigned short* nw = un + w * (16 * NNS);
#pragma unroll
  for (int n2 = 0; n2 < 8; n2++)
#pragma unroll
    for (int rg = 0; rg < 4; rg++)
      nw[(quad * 4 + rg) * NNS + n2 * 16 + l15] = f2bf(o[n2][rg] * Lp[rg]);
  short8 qf2[4];
#pragma unroll
  for (int k = 0; k < 4; k++)
    qf2[k] = *(const short8*)(nw + l15 * NNS + k * 32 + quad * 8);

  // ---------------- phase 2: Q=nn, K=e1, V=sp scalar ----------------
  float L2[4] = {0.f, 0.f, 0.f, 0.f}, tp[4] = {0.f, 0.f, 0.f, 0.f};
  for (int st = 0; st < 16; st++) {
    const int sbase = st * 64;
    __syncthreads();
    {
      const unsigned short* src = ebf + (size_t)(i * T_ + sbase) * D_;
#pragma unroll
      for (int c = 0; c < 4; c++) {
        int idx = c * 256 + tid;
        int row = idx >> 4, cp = (idx & 15) * 8;
        *(u16x8*)&kt[row * KTS + cp] = *(const u16x8*)(src + row * D_ + cp);
      }
    }
    __syncthreads();

    const float* nsp = ns + i * T_ + sbase + l15;
    const float* spp = steps + i * T_ + sbase + l15;
#pragma unroll
    for (int n = 0; n < 4; n++) {
      f32x4 acc = (f32x4){0.f, 0.f, 0.f, 0.f};
#pragma unroll
      for (int k = 0; k < 4; k++) {
        short8 bf = *(const short8*)(ktb + n * 16 * KTS + k * 32);
        acc = __builtin_amdgcn_mfma_f32_16x16x32_bf16(qf2[k], bf, acc, 0, 0, 0);
      }
      float nv = nsp[n * 16], sv = spp[n * 16];
#pragma unroll
      for (int rg = 0; rg < 4; rg++) {
        float pv = __builtin_amdgcn_exp2f(acc[rg] - nv);
        L2[rg] += pv;
        tp[rg] += pv * sv;
      }
    }
  }

  // epilogue: per-row combine, MSE
  float local = 0.f;
#pragma unroll
  for (int rg = 0; rg < 4; rg++) {
    float L = quadSum(L2[rg]);
    float t = quadSum(tp[rg]);
    float pred = t / L;
    float tt = steps[i * T_ + t0 + w * 16 + quad * 4 + rg];
    float d = pred - tt;
    local += d * d;
  }
  if (l15 != 0) local = 0.f;
  local = waveSum(local);
  if (lane == 0) bl[w] = local;
  __syncthreads();
  if (tid == 0) atomicAdd(loss_acc, bl[0] + bl[1] + bl[2] + bl[3]);
}

__global__ void finalize_kernel(const float* __restrict__ acc, float* __restrict__ out) {
  out[0] = acc[0] * (1.0f / (float)(NPAIR * T_));
}

extern "C" void kernel_launch(void* const* d_in, const int* in_sizes, int n_in,
                              void* d_out, int out_size, void* d_ws, size_t ws_size,
                              hipStream_t stream) {
  const float* embs = (const float*)d_in[0];
  const int* frame_idxs = (const int*)d_in[1];
  const int* video_len = (const int*)d_in[2];
  float* out = (float*)d_out;

  char* ws = (char*)d_ws;
  float* acc = (float*)ws;                                   // @0
  float* ns = (float*)(ws + 1024);                           // 8192 f32
  float* steps = (float*)(ws + 1024 + 32768);                // 8192 f32
  unsigned short* ebf = (unsigned short*)(ws + 1024 + 65536);       // 2 MB
  unsigned short* ebfT = ebf + (size_t)8 * T_ * D_;                 // 2 MB

  hipMemsetAsync(acc, 0, 256, stream);
  norm_kernel<<<dim3(2048), dim3(256), 0, stream>>>(embs, frame_idxs, video_len, ns, steps);
  convert_kernel<<<dim3(16, 8), dim3(256), 0, stream>>>(embs, ebf, ebfT);
  tcc_main<<<dim3(T_ / 64, NPAIR), dim3(256), 0, stream>>>(embs, ebf, ebfT, ns, steps, acc);
  finalize_kernel<<<1, 1, 0, stream>>>(acc, out);
}

// Round 3
// 168.509 us; speedup vs baseline: 7.5175x; 1.3610x over previous
//
#include <hip/hip_runtime.h>

// B=8, T=1024, D=128, TEMP=0.1, WEIGHT=1.0. 56 ordered pairs (i,j), i!=j.
// z1[t,s] = QSCALE*(e1_t . e2_s) - ns[s],  ns = |e2_s|^2*(1/12.8)*log2e  (row-const dropped)
// p = exp2(z1); nn_t = sum p*e2_s / sum p
// z2[t,s] = QSCALE*(nn_t . e1_s) - ns_i[s]; time_pred = sum exp2(z2)*sp_s / sum exp2(z2)
// loss = mean (pred - sp_t)^2.  No max-subtraction needed: z in [-40,+15] provably.
//
// R3 structure: fragment-layout global buffers (A/B frags coalesced 16B/lane),
// 32x32x16 MFMA, NO __syncthreads in main loop, wave-private LDS only for the
// P / nn C->A layout transpose. 64-thread blocks, grid 56*32.

#define T_ 1024
#define D_ 128
#define NPAIR 56
#define QSCALE 0.11271055006945026f   // (1/12.8)*log2(e)  (applied to 2*dot via c*2? no:)
// NOTE: z = (2*dot - |k|^2)/12.8 * log2e = dot*(2/12.8)*log2e - |k|^2*(1/12.8)*log2e
#define DOTSCALE 0.22542110013890052f // (2/12.8)*log2(e)
#define NSCALE 0.11271055006945026f   // (1/12.8)*log2(e)

typedef short short8 __attribute__((ext_vector_type(8)));
typedef unsigned short u16x8 __attribute__((ext_vector_type(8)));
typedef float f32x16 __attribute__((ext_vector_type(16)));

#define BATCH_STRIDE 131072  // shorts per batch in frag layouts (256 chunks * 512)

__device__ __forceinline__ unsigned short f2bf(float f) {
  unsigned u = __float_as_uint(f);
  u += 0x7fff + ((u >> 16) & 1);  // RNE
  return (unsigned short)(u >> 16);
}

__device__ __forceinline__ float waveSum(float v) {
#pragma unroll
  for (int k = 32; k >= 1; k >>= 1) v += __shfl_xor(v, k, 64);
  return v;
}
__device__ __forceinline__ float halfSum(float v) {  // reduce across lanes sharing bit5
  v += __shfl_xor(v, 1, 64); v += __shfl_xor(v, 2, 64);
  v += __shfl_xor(v, 4, 64); v += __shfl_xor(v, 8, 64);
  v += __shfl_xor(v, 16, 64);
  return v;
}

// ---- fused: fp32 -> bf16 frag layouts + norms + steps ----
// fragA (row-frag): chunk c = (t>>5)*8 + (d>>4); lane = ((d>>3)&1)*32 + (t&31); elem = d&7
// fragT (V^T frag): chunk c = (d>>5)*64 + (t>>4); lane = ((t>>3)&1)*32 + (d&31); elem = t&7
__global__ __launch_bounds__(256) void convert_kernel(
    const float* __restrict__ embs, const int* __restrict__ fi,
    const int* __restrict__ vl, unsigned short* __restrict__ ebfF,
    unsigned short* __restrict__ ebfT, float* __restrict__ ns,
    float* __restrict__ steps) {
  __shared__ unsigned short tileS[32 * 136];
  __shared__ float psum[32][8];
  const int b = blockIdx.x >> 5;
  const int t0 = (blockIdx.x & 31) * 32;
  const int tid = threadIdx.x;
  const int row = tid >> 3, seg = tid & 7;   // row 0..31, seg*16 = d-chunk

  const float* src = embs + (size_t)(b * T_ + t0 + row) * D_ + seg * 16;
  float4 g[4];
#pragma unroll
  for (int k = 0; k < 4; k++) g[k] = ((const float4*)src)[k];
  float s = 0.f;
  unsigned short v[16];
#pragma unroll
  for (int k = 0; k < 4; k++) {
    s += g[k].x * g[k].x + g[k].y * g[k].y + g[k].z * g[k].z + g[k].w * g[k].w;
    v[k * 4 + 0] = f2bf(g[k].x); v[k * 4 + 1] = f2bf(g[k].y);
    v[k * 4 + 2] = f2bf(g[k].z); v[k * 4 + 3] = f2bf(g[k].w);
  }
  psum[row][seg] = s;

  // fragA store: chunk (t0>>5)*8 + seg, lanes row and 32+row
  unsigned short* dstA = ebfF + (size_t)b * BATCH_STRIDE + (size_t)((t0 >> 5) * 8 + seg) * 512;
  *(u16x8*)(dstA + row * 8) = *(const u16x8*)&v[0];
  *(u16x8*)(dstA + (32 + row) * 8) = *(const u16x8*)&v[8];

  // LDS tile for transpose (stride 136 shorts = 272 B)
  *(u16x8*)&tileS[row * 136 + seg * 16] = *(const u16x8*)&v[0];
  *(u16x8*)&tileS[row * 136 + seg * 16 + 8] = *(const u16x8*)&v[8];
  __syncthreads();

  if (tid < 32) {
    float t = 0.f;
#pragma unroll
    for (int k = 0; k < 8; k++) t += psum[tid][k];
    int gr = b * T_ + t0 + tid;
    ns[gr] = t * NSCALE;
    steps[gr] = (float)fi[gr] / (float)vl[b];
  }

  // fragT: 8 chunks per block; thread -> (chunk c8, two lanes)
  const int c8 = tid >> 5;                  // 0..7
  const int d0t = (c8 & 3) * 32, sc = c8 >> 2;
  const int chunk = (d0t >> 5) * 64 + (t0 >> 4) + sc;
  unsigned short* dstT = ebfT + (size_t)b * BATCH_STRIDE + (size_t)chunk * 512;
  const int dd = d0t + (tid & 31);
#pragma unroll
  for (int half = 0; half < 2; half++) {
    const int lane = half * 32 + (tid & 31);
    const int sl = sc * 16 + half * 8;
    u16x8 w;
#pragma unroll
    for (int jj = 0; jj < 8; jj++) w[jj] = tileS[(sl + jj) * 136 + dd];
    *(u16x8*)(dstT + lane * 8) = w;
  }
}

__global__ __launch_bounds__(64, 2) void tcc_main(
    const unsigned short* __restrict__ ebfF, const unsigned short* __restrict__ ebfT,
    const float* __restrict__ ns, const float* __restrict__ steps,
    float* __restrict__ loss_acc) {
  __shared__ unsigned short buf[32 * 136];  // wave-private: p (stride 72) / nn (stride 136)

  const int bx = blockIdx.x;
  const int pair = bx >> 5;
  const int tile = bx & 31;
  const int i = pair / 7;
  const int r = pair % 7;
  const int j = r + (r >= i ? 1 : 0);
  const int t0 = tile * 32;
  const int l = threadIdx.x;
  const int l31 = l & 31;
  const int lh = l >> 5;

  // Q A-frags: e1 rows t0..t0+31 (raw bf16; DOTSCALE applied in exp-fma)
  short8 qf[8];
  {
    const unsigned short* qb = ebfF + (size_t)i * BATCH_STRIDE + (size_t)((t0 >> 5) * 8) * 512 + l * 8;
#pragma unroll
    for (int kc = 0; kc < 8; kc++) qf[kc] = *(const short8*)(qb + kc * 512);
  }

  f32x16 o[4];
#pragma unroll
  for (int n2 = 0; n2 < 4; n2++)
#pragma unroll
    for (int z = 0; z < 16; z++) o[n2][z] = 0.f;
  float L1a[16];
#pragma unroll
  for (int z = 0; z < 16; z++) L1a[z] = 0.f;

  const unsigned short* kb1 = ebfF + (size_t)j * BATCH_STRIDE + l * 8;
  const unsigned short* vb1 = ebfT + (size_t)j * BATCH_STRIDE + l * 8;
  const float* nsj = ns + j * T_;

  // ---------------- phase 1: Q=e1, K=V=e2; no barriers ----------------
  for (int st = 0; st < 16; st++) {
    f32x16 c0, c1;
#pragma unroll
    for (int z = 0; z < 16; z++) { c0[z] = 0.f; c1[z] = 0.f; }
    const unsigned short* kp = kb1 + (size_t)(st * 16) * 512;
#pragma unroll
    for (int kc = 0; kc < 8; kc++) {
      short8 b0 = *(const short8*)(kp + kc * 512);
      short8 b1 = *(const short8*)(kp + (8 + kc) * 512);
      c0 = __builtin_amdgcn_mfma_f32_32x32x16_bf16(qf[kc], b0, c0, 0, 0, 0);
      c1 = __builtin_amdgcn_mfma_f32_32x32x16_bf16(qf[kc], b1, c1, 0, 0, 0);
    }
    const float ns0 = nsj[st * 64 + l31];
    const float ns1 = nsj[st * 64 + 32 + l31];
#pragma unroll
    for (int rg = 0; rg < 16; rg++) {
      const int row = (rg & 3) + 8 * (rg >> 2) + 4 * lh;
      float p0 = __builtin_amdgcn_exp2f(c0[rg] * DOTSCALE - ns0);
      float p1 = __builtin_amdgcn_exp2f(c1[rg] * DOTSCALE - ns1);
      L1a[rg] += p0 + p1;
      buf[row * 72 + l31] = f2bf(p0);
      buf[row * 72 + 32 + l31] = f2bf(p1);
    }
    // P A-frags (wave-private LDS round-trip), then PV
    short8 pf[4];
#pragma unroll
    for (int kc2 = 0; kc2 < 4; kc2++)
      pf[kc2] = *(const short8*)(buf + l31 * 72 + kc2 * 16 + lh * 8);
    const unsigned short* vp = vb1 + (size_t)(st * 4) * 512;
#pragma unroll
    for (int n2 = 0; n2 < 4; n2++) {
#pragma unroll
      for (int kc2 = 0; kc2 < 4; kc2++) {
        short8 bv = *(const short8*)(vp + (size_t)(n2 * 64 + kc2) * 512);
        o[n2] = __builtin_amdgcn_mfma_f32_32x32x16_bf16(pf[kc2], bv, o[n2], 0, 0, 0);
      }
    }
  }

  // normalize nn -> wave-private LDS (stride 136), reload as A-frags
#pragma unroll
  for (int rg = 0; rg < 16; rg++) L1a[rg] = 1.0f / halfSum(L1a[rg]);
#pragma unroll
  for (int n2 = 0; n2 < 4; n2++)
#pragma unroll
    for (int rg = 0; rg < 16; rg++) {
      const int row = (rg & 3) + 8 * (rg >> 2) + 4 * lh;
      buf[row * 136 + n2 * 32 + l31] = f2bf(o[n2][rg] * L1a[rg]);
    }
  short8 qf2[8];
#pragma unroll
  for (int kc = 0; kc < 8; kc++)
    qf2[kc] = *(const short8*)(buf + l31 * 136 + kc * 16 + lh * 8);

  // ---------------- phase 2: Q=nn, K=e1, V=sp scalar ----------------
  float L2a[16], tpa[16];
#pragma unroll
  for (int z = 0; z < 16; z++) { L2a[z] = 0.f; tpa[z] = 0.f; }
  const unsigned short* kb2 = ebfF + (size_t)i * BATCH_STRIDE + l * 8;
  const float* nsi = ns + i * T_;
  const float* spi = steps + i * T_;

  for (int st = 0; st < 16; st++) {
    f32x16 c0, c1;
#pragma unroll
    for (int z = 0; z < 16; z++) { c0[z] = 0.f; c1[z] = 0.f; }
    const unsigned short* kp = kb2 + (size_t)(st * 16) * 512;
#pragma unroll
    for (int kc = 0; kc < 8; kc++) {
      short8 b0 = *(const short8*)(kp + kc * 512);
      short8 b1 = *(const short8*)(kp + (8 + kc) * 512);
      c0 = __builtin_amdgcn_mfma_f32_32x32x16_bf16(qf2[kc], b0, c0, 0, 0, 0);
      c1 = __builtin_amdgcn_mfma_f32_32x32x16_bf16(qf2[kc], b1, c1, 0, 0, 0);
    }
    const float ns0 = nsi[st * 64 + l31], sp0 = spi[st * 64 + l31];
    const float ns1 = nsi[st * 64 + 32 + l31], sp1 = spi[st * 64 + 32 + l31];
#pragma unroll
    for (int rg = 0; rg < 16; rg++) {
      float p0 = __builtin_amdgcn_exp2f(c0[rg] * DOTSCALE - ns0);
      float p1 = __builtin_amdgcn_exp2f(c1[rg] * DOTSCALE - ns1);
      L2a[rg] += p0 + p1;
      tpa[rg] += p0 * sp0 + p1 * sp1;
    }
  }

  // epilogue: reduce, MSE, one atomic per wave
  float local = 0.f;
#pragma unroll
  for (int rg = 0; rg < 16; rg++) {
    float Lv = halfSum(L2a[rg]);
    float Tv = halfSum(tpa[rg]);
    const int row = (rg & 3) + 8 * (rg >> 2) + 4 * lh;
    float pred = Tv / Lv;
    float tt = steps[i * T_ + t0 + row];
    float d = pred - tt;
    local += d * d;
  }
  if (l31 != 0) local = 0.f;
  local = waveSum(local);
  if (l == 0) atomicAdd(loss_acc, local);
}

__global__ void finalize_kernel(const float* __restrict__ acc, float* __restrict__ out) {
  out[0] = acc[0] * (1.0f / (float)(NPAIR * T_));
}

extern "C" void kernel_launch(void* const* d_in, const int* in_sizes, int n_in,
                              void* d_out, int out_size, void* d_ws, size_t ws_size,
                              hipStream_t stream) {
  const float* embs = (const float*)d_in[0];
  const int* frame_idxs = (const int*)d_in[1];
  const int* video_len = (const int*)d_in[2];
  float* out = (float*)d_out;

  char* ws = (char*)d_ws;
  float* acc = (float*)ws;                                     // @0
  float* ns = (float*)(ws + 1024);                             // 8192 f32
  float* steps = (float*)(ws + 1024 + 32768);                  // 8192 f32
  unsigned short* ebfF = (unsigned short*)(ws + 1024 + 65536); // 2 MB frag layout
  unsigned short* ebfT = ebfF + (size_t)8 * BATCH_STRIDE;      // 2 MB transposed frag

  hipMemsetAsync(acc, 0, 256, stream);
  convert_kernel<<<dim3(256), dim3(256), 0, stream>>>(embs, frame_idxs, video_len,
                                                      ebfF, ebfT, ns, steps);
  tcc_main<<<dim3(NPAIR * 32), dim3(64), 0, stream>>>(ebfF, ebfT, ns, steps, acc);
  finalize_kernel<<<1, 1, 0, stream>>>(acc, out);
}